// Round 9
// baseline (77.061 us; speedup 1.0000x reference)
//
#include <hip/hip_runtime.h>

#define NB 524288
#define NC 32
#define NQ 16          // center pairs
#define EPSV 1e-4f
#define DTB 0.12f      // DT * BETA
#define CLAMPV 3.0f
#define NSTEPS 4

typedef float f32x2 __attribute__((ext_vector_type(2)));

__device__ __forceinline__ f32x2 pk_fma(f32x2 a, f32x2 b, f32x2 c) {
    return __builtin_elementwise_fma(a, b, c);
}

// ws layout (floats):
//   [0, 256)   : ct2[q*16 + d*2 + j] = -2 * centers[2q+j][d]   (pre-scaled!)
//   [256, 320) : per q: {|c_2q|^2+EPS, |c_2q+1|^2+EPS, mu_2q, mu_2q+1}
__global__ void prep_kernel(const float* __restrict__ centers,
                            const float* __restrict__ mus,
                            float* __restrict__ ws) {
    int q = threadIdx.x;
    if (q < NQ) {
        float n0 = EPSV, n1 = EPSV;
        #pragma unroll
        for (int d = 0; d < 8; ++d) {
            float a = centers[(2 * q) * 8 + d];
            float b = centers[(2 * q + 1) * 8 + d];
            ws[q * 16 + d * 2 + 0] = -2.0f * a;
            ws[q * 16 + d * 2 + 1] = -2.0f * b;
            n0 = fmaf(a, a, n0);
            n1 = fmaf(b, b, n1);
        }
        ws[256 + q * 4 + 0] = n0;
        ws[256 + q * 4 + 1] = n1;
        ws[256 + q * 4 + 2] = mus[2 * q];
        ws[256 + q * 4 + 3] = mus[2 * q + 1];
    }
}

__global__ __launch_bounds__(256, 4) void pm_kernel(
    const float* __restrict__ z_in,
    const float* __restrict__ ws,
    float* __restrict__ out)
{
    const int i = blockIdx.x * 256 + threadIdx.x;

    const float4* zp = (const float4*)z_in;
    float4 a0 = zp[(size_t)i * 2], a1 = zp[(size_t)i * 2 + 1];
    // z kept as splat pairs {z_d, z_d} so all center math is packed
    f32x2 zs[8] = {{a0.x, a0.x}, {a0.y, a0.y}, {a0.z, a0.z}, {a0.w, a0.w},
                   {a1.x, a1.x}, {a1.y, a1.y}, {a1.z, a1.z}, {a1.w, a1.w}};

    // Wave-uniform reads -> s_load of consecutive SGPR pairs.
    const f32x2* ct2 = (const f32x2*)ws;          // ct2[q*8 + d] = {-2c_d, -2c'_d}
    const f32x2* bm  = (const f32x2*)(ws + 256);  // bm[2q]=bb2, bm[2q+1]=mu2

    #pragma unroll 1
    for (int s = 0; s < NSTEPS; ++s) {
        // zz in both lanes
        f32x2 zz2 = zs[0] * zs[0];
        #pragma unroll
        for (int d = 1; d < 8; ++d) zz2 = pk_fma(zs[d], zs[d], zz2);

        // ---- PASS 1: 16 independent packed r^2 chains ----
        // r2 = (zz + |c|^2 + eps) + sum_d z_d * (-2 c_d)
        f32x2 rr[NQ];
        #pragma unroll
        for (int q = 0; q < NQ; ++q) {
            f32x2 acc = zz2 + bm[q * 2];
            #pragma unroll
            for (int d = 0; d < 8; ++d)
                acc = pk_fma(zs[d], ct2[q * 8 + d], acc);
            rr[q] = acc;
        }

        // ---- PASS 2: 32 independent v_rsq_f32, in-place ----
        #pragma unroll
        for (int q = 0; q < NQ; ++q) {
            rr[q].x = __builtin_amdgcn_rsqf(rr[q].x);
            rr[q].y = __builtin_amdgcn_rsqf(rr[q].y);
        }

        // ---- PASS 3: accumulate n, sw, gc (against -2c) ----
        f32x2 n2  = {0.f, 0.f};
        f32x2 sw2 = {0.f, 0.f};
        f32x2 gc[8] = {{0.f,0.f},{0.f,0.f},{0.f,0.f},{0.f,0.f},
                       {0.f,0.f},{0.f,0.f},{0.f,0.f},{0.f,0.f}};
        #pragma unroll
        for (int q = 0; q < NQ; ++q) {
            f32x2 rinv = rr[q];
            f32x2 t  = bm[q * 2 + 1] * rinv;   // mu / r
            f32x2 ri = rinv * rinv;
            f32x2 w3 = t * ri;                 // mu / r^3
            n2  = n2 + t;
            sw2 = sw2 + w3;
            #pragma unroll
            for (int d = 0; d < 8; ++d)
                gc[d] = pk_fma(w3, ct2[q * 8 + d], gc[d]);  // gc' = -2 * gc_true
        }

        // z_new = alpha*z + beta*(gc'.x + gc'.y)  [HORIZONTAL SUM — r8 bug fix]
        // alpha = 1 - scale*sw, beta = -scale/2
        float n  = 1.0f + n2.x + n2.y;
        float sw = sw2.x + sw2.y;
        float scale = DTB * __builtin_amdgcn_rcpf(n);   // v_rcp_f32
        float alpha = fmaf(-scale, sw, 1.0f);
        float beta  = -0.5f * scale;
        #pragma unroll
        for (int d = 0; d < 8; ++d) {
            float gtot = gc[d].x + gc[d].y;              // combine even/odd halves
            float zn = fmaf(beta, gtot, alpha * zs[d].x);
            zn = fminf(fmaxf(zn, -CLAMPV), CLAMPV);
            zs[d] = (f32x2){zn, zn};                     // re-splat
        }
    }

    float4 o0 = {zs[0].x, zs[1].x, zs[2].x, zs[3].x};
    float4 o1 = {zs[4].x, zs[5].x, zs[6].x, zs[7].x};
    float4* op = (float4*)out;
    op[(size_t)i * 2]     = o0;
    op[(size_t)i * 2 + 1] = o1;
}

extern "C" void kernel_launch(void* const* d_in, const int* in_sizes, int n_in,
                              void* d_out, int out_size, void* d_ws, size_t ws_size,
                              hipStream_t stream) {
    const float* z       = (const float*)d_in[0];
    const float* centers = (const float*)d_in[1];
    const float* mus     = (const float*)d_in[2];
    float* out           = (float*)d_out;
    float* ws            = (float*)d_ws;

    prep_kernel<<<1, 64, 0, stream>>>(centers, mus, ws);
    pm_kernel<<<NB / 256, 256, 0, stream>>>(z, ws, out);
}

// Round 10
// 52.710 us; speedup vs baseline: 1.4620x; 1.4620x over previous
//
#include <hip/hip_runtime.h>

#define NB 524288
#define NC 32
#define NP 4           // points per thread
#define EPSV 1e-4f
#define DTB 0.12f      // DT * BETA
#define CLAMPV 3.0f
#define NSTEPS 4

typedef float f32x2 __attribute__((ext_vector_type(2)));

__device__ __forceinline__ f32x2 pk_fma(f32x2 a, f32x2 b, f32x2 c) {
    return __builtin_elementwise_fma(a, b, c);
}

// ws: bb[c] = |centers[c]|^2 + EPS  (32 floats)
__global__ void prep_kernel(const float* __restrict__ centers,
                            float* __restrict__ ws) {
    int c = threadIdx.x;
    if (c < NC) {
        float n0 = EPSV;
        #pragma unroll
        for (int d = 0; d < 8; ++d) {
            float a = centers[c * 8 + d];
            n0 = fmaf(a, a, n0);
        }
        ws[c] = n0;
    }
}

__global__ __launch_bounds__(256, 2) void pm_kernel(
    const float* __restrict__ z_in,
    const float* __restrict__ centers,
    const float* __restrict__ mus,
    const float* __restrict__ bbw,
    float* __restrict__ out)
{
    const int tid = blockIdx.x * 256 + threadIdx.x;

    const float4* zp = (const float4*)z_in;
    f32x2 z[NP][4];
    #pragma unroll
    for (int p = 0; p < NP; ++p) {
        const size_t idx = (size_t)(tid + p * (NB / NP)) * 2;
        float4 a0 = zp[idx], a1 = zp[idx + 1];
        z[p][0] = (f32x2){a0.x, a0.y};
        z[p][1] = (f32x2){a0.z, a0.w};
        z[p][2] = (f32x2){a1.x, a1.y};
        z[p][3] = (f32x2){a1.z, a1.w};
    }

    // Wave-uniform reads -> s_load into SGPRs.
    const f32x2* cp = (const f32x2*)centers;

    #pragma unroll 1
    for (int s = 0; s < NSTEPS; ++s) {
        float zz[NP];
        float n[NP], sw[NP];
        f32x2 gc[NP][4];
        #pragma unroll
        for (int p = 0; p < NP; ++p) {
            f32x2 q = z[p][0] * z[p][0];
            q = pk_fma(z[p][1], z[p][1], q);
            q = pk_fma(z[p][2], z[p][2], q);
            q = pk_fma(z[p][3], z[p][3], q);
            zz[p] = q.x + q.y;
            n[p] = 1.0f; sw[p] = 0.0f;
            gc[p][0] = (f32x2){0.f, 0.f}; gc[p][1] = (f32x2){0.f, 0.f};
            gc[p][2] = (f32x2){0.f, 0.f}; gc[p][3] = (f32x2){0.f, 0.f};
        }

        #pragma unroll
        for (int c = 0; c < NC; ++c) {
            const f32x2 c0 = cp[c * 4 + 0], c1 = cp[c * 4 + 1];
            const f32x2 c2 = cp[c * 4 + 2], c3 = cp[c * 4 + 3];
            const float mu = mus[c];
            const float bb = bbw[c];     // |c|^2 + eps, from SGPR

            #pragma unroll
            for (int p = 0; p < NP; ++p) {
                f32x2 acc = z[p][0] * c0;
                acc = pk_fma(z[p][1], c1, acc);
                acc = pk_fma(z[p][2], c2, acc);
                acc = pk_fma(z[p][3], c3, acc);
                float dot = acc.x + acc.y;
                float r2 = fmaf(-2.0f, dot, zz[p] + bb);
                float rinv = __builtin_amdgcn_rsqf(r2);  // v_rsq_f32
                float w = mu * rinv;                     // mu / r
                n[p] += w;
                float w3 = (w * rinv) * rinv;            // mu / r^3
                sw[p] += w3;
                f32x2 w3v = {w3, w3};
                gc[p][0] = pk_fma(w3v, c0, gc[p][0]);
                gc[p][1] = pk_fma(w3v, c1, gc[p][1]);
                gc[p][2] = pk_fma(w3v, c2, gc[p][2]);
                gc[p][3] = pk_fma(w3v, c3, gc[p][3]);
            }
        }

        const f32x2 lo = {-CLAMPV, -CLAMPV}, hi = {CLAMPV, CLAMPV};
        #pragma unroll
        for (int p = 0; p < NP; ++p) {
            float scale = DTB * __builtin_amdgcn_rcpf(n[p]);  // v_rcp_f32
            f32x2 nsw = {-sw[p], -sw[p]};
            f32x2 sv  = {scale, scale};
            #pragma unroll
            for (int k = 0; k < 4; ++k) {
                f32x2 g = pk_fma(nsw, z[p][k], gc[p][k]);
                z[p][k] = pk_fma(sv, g, z[p][k]);
                z[p][k] = __builtin_elementwise_min(
                              __builtin_elementwise_max(z[p][k], lo), hi);
            }
        }
    }

    float4* op = (float4*)out;
    #pragma unroll
    for (int p = 0; p < NP; ++p) {
        const size_t idx = (size_t)(tid + p * (NB / NP)) * 2;
        float4 o0 = {z[p][0].x, z[p][0].y, z[p][1].x, z[p][1].y};
        float4 o1 = {z[p][2].x, z[p][2].y, z[p][3].x, z[p][3].y};
        op[idx]     = o0;
        op[idx + 1] = o1;
    }
}

extern "C" void kernel_launch(void* const* d_in, const int* in_sizes, int n_in,
                              void* d_out, int out_size, void* d_ws, size_t ws_size,
                              hipStream_t stream) {
    const float* z       = (const float*)d_in[0];
    const float* centers = (const float*)d_in[1];
    const float* mus     = (const float*)d_in[2];
    float* out           = (float*)d_out;
    float* ws            = (float*)d_ws;

    prep_kernel<<<1, 64, 0, stream>>>(centers, ws);
    pm_kernel<<<NB / NP / 256, 256, 0, stream>>>(z, centers, mus, ws, out);
}

// Round 12
// 41.516 us; speedup vs baseline: 1.8562x; 1.2696x over previous
//
#include <hip/hip_runtime.h>
#include <stdint.h>

#define NB 524288
#define NC 32
#define EPSV 1e-4f
#define DTB 0.12f      // DT * BETA
#define CLAMPV 3.0f
#define NSTEPS 4

typedef float f32x16 __attribute__((ext_vector_type(16)));
typedef short short8 __attribute__((ext_vector_type(8)));

union FragU { uint32_t u[4]; short8 s; uint4 q; };

__device__ __forceinline__ uint32_t pkbf16(float a, float b) {
    uint32_t r;
    asm("v_cvt_pk_bf16_f32 %0, %1, %2" : "=v"(r) : "v"(a), "v"(b));
    return r;   // low16 = bf16(a), high16 = bf16(b)
}
__device__ __forceinline__ float lo16f(uint32_t w) { return __uint_as_float(w << 16); }
__device__ __forceinline__ float hi16f(uint32_t w) { return __uint_as_float(w & 0xffff0000u); }
__device__ __forceinline__ float sx32(float v) { return __shfl_xor(v, 32); }
__device__ __forceinline__ uint32_t sx32u(uint32_t v) { return (uint32_t)__shfl_xor((int)v, 32); }

// ws layout:
//  uint4 [0..63]    A1_hi : rows=centers, k<8: -2c/mu^2, k=8: (|c|^2+eps)/mu^2, k>=9: 0
//  uint4 [64..127]  A1_lo
//  uint4 [128..191] A2_hi chunk0 : rows 0..7 = c_d/mu^2, row 8 = 1/mu^2; k=centers 0..15
//  uint4 [192..255] A2_hi chunk1 (centers 16..31)
//  uint4 [256..319] A2_lo chunk0
//  uint4 [320..383] A2_lo chunk1
//  float [1536..1567] imtab: imtab[h*16+r] = 1/mu^2 of center crow(r,h)=(r&3)+8*(r>>2)+4*h
__global__ void prep_kernel(const float* __restrict__ centers,
                            const float* __restrict__ mus,
                            uint4* __restrict__ wsu) {
    int t = threadIdx.x;
    if (t >= 64) return;
    int row = t & 31, part = t >> 5;

    // ---- A1 (rows = centers) ----
    float mu = mus[row];
    float im2 = 1.0f / (mu * mu);
    float c[8];
    float bb = EPSV;
    #pragma unroll
    for (int d = 0; d < 8; ++d) { c[d] = centers[row * 8 + d]; bb = fmaf(c[d], c[d], bb); }
    float v[8];
    #pragma unroll
    for (int i = 0; i < 8; ++i) {
        int k = part * 8 + i;
        v[i] = (k < 8) ? (-2.0f * c[k] * im2) : (k == 8) ? (bb * im2) : 0.0f;  // zz slot removed
    }
    uint32_t h[4], l[4];
    #pragma unroll
    for (int j = 0; j < 4; ++j) {
        float a = v[2 * j], b = v[2 * j + 1];
        h[j] = pkbf16(a, b);
        l[j] = pkbf16(a - lo16f(h[j]), b - hi16f(h[j]));
    }
    wsu[t]      = make_uint4(h[0], h[1], h[2], h[3]);
    wsu[64 + t] = make_uint4(l[0], l[1], l[2], l[3]);

    // ---- A2 (rows = dims 0..7, row 8 = sw-row; k = centers) ----
    #pragma unroll
    for (int ch = 0; ch < 2; ++ch) {
        float v2[8];
        #pragma unroll
        for (int i = 0; i < 8; ++i) {
            int ci = ch * 16 + part * 8 + i;
            float muc = mus[ci];
            float im2c = 1.0f / (muc * muc);
            v2[i] = (row < 8) ? (centers[ci * 8 + row] * im2c) : (row == 8) ? im2c : 0.0f;
        }
        uint32_t h2[4], l2[4];
        #pragma unroll
        for (int j = 0; j < 4; ++j) {
            float a = v2[2 * j], b = v2[2 * j + 1];
            h2[j] = pkbf16(a, b);
            l2[j] = pkbf16(a - lo16f(h2[j]), b - hi16f(h2[j]));
        }
        wsu[128 + ch * 64 + t] = make_uint4(h2[0], h2[1], h2[2], h2[3]);
        wsu[256 + ch * 64 + t] = make_uint4(l2[0], l2[1], l2[2], l2[3]);
    }

    // ---- imtab: per-(hi,reg) 1/mu^2, fp32 ----
    if (t < 32) {
        int h2i = t >> 4, r = t & 15;
        int ci = (r & 3) + 8 * (r >> 2) + 4 * h2i;
        float muc = mus[ci];
        ((float*)wsu)[1536 + t] = 1.0f / (muc * muc);
    }
}

__global__ __launch_bounds__(256, 3) void pm_kernel(
    const float* __restrict__ z_in,
    const uint4* __restrict__ wsu,
    float* __restrict__ out)
{
    const int tid  = threadIdx.x;
    const int wid  = tid >> 6;
    const int lane = tid & 63;
    const int hi   = lane >> 5;          // half-wave id
    const int col  = lane & 31;          // point within tile
    const int point = blockIdx.x * 128 + wid * 32 + col;

    // constant fragments (L2-resident)
    FragU A1h, A1l, A2h0, A2h1, A2l0, A2l1;
    A1h.q  = wsu[lane];        A1l.q  = wsu[64 + lane];
    A2h0.q = wsu[128 + lane];  A2h1.q = wsu[192 + lane];
    A2l0.q = wsu[256 + lane];  A2l1.q = wsu[320 + lane];

    // per-lane fp32 constants: imv[r] = 1/mu^2 of center crow(r,hi)
    const float* imt = ((const float*)wsu) + 1536 + hi * 16;
    float imv[16];
    #pragma unroll
    for (int r = 0; r < 16; ++r) imv[r] = imt[r];

    // z: this lane owns dims [hi*4 .. hi*4+3] (za); partner half via shfl (zb)
    const float4* zp4 = (const float4*)z_in;
    float4 hvec = zp4[(size_t)point * 2 + hi];
    float za0 = hvec.x, za1 = hvec.y, za2 = hvec.z, za3 = hvec.w;
    float zb0 = sx32(za0), zb1 = sx32(za1), zb2 = sx32(za2), zb3 = sx32(za3);

    #pragma unroll 1
    for (int s = 0; s < NSTEPS; ++s) {
        // zz = |z|^2 (fp32, stays OUT of the bf16 GEMM)
        float zz = za0 * za0;
        zz = fmaf(za1, za1, zz); zz = fmaf(za2, za2, zz); zz = fmaf(za3, za3, zz);
        zz = fmaf(zb0, zb0, zz); zz = fmaf(zb1, zb1, zz);
        zz = fmaf(zb2, zb2, zz); zz = fmaf(zb3, zb3, zz);

        // ---- B1 (z_ext, col = point): hi0 lanes carry z dims 0..7; hi1 carry [1,0,...] ----
        uint32_t w0 = pkbf16(za0, za1), w1 = pkbf16(za2, za3);
        uint32_t w2 = pkbf16(zb0, zb1), w3w = pkbf16(zb2, zb3);
        uint32_t q0 = pkbf16(1.0f, 0.0f);   // k=8: exact 1; k=9: 0
        uint32_t w0l = pkbf16(za0 - lo16f(w0), za1 - hi16f(w0));
        uint32_t w1l = pkbf16(za2 - lo16f(w1), za3 - hi16f(w1));
        uint32_t w2l = pkbf16(zb0 - lo16f(w2), zb1 - hi16f(w2));
        uint32_t w3l = pkbf16(zb2 - lo16f(w3w), zb3 - hi16f(w3w));

        FragU B1h, B1l;
        B1h.u[0] = hi ? q0 : w0;   B1h.u[1] = hi ? 0u : w1;
        B1h.u[2] = hi ? 0u : w2;   B1h.u[3] = hi ? 0u : w3w;
        B1l.u[0] = hi ? 0u : w0l;  B1l.u[1] = hi ? 0u : w1l;
        B1l.u[2] = hi ? 0u : w2l;  B1l.u[3] = hi ? 0u : w3l;

        // ---- GEMM1: D1[center][point] = (bb - 2 z.c)/mu^2, full 4-term split ----
        f32x16 D1 = {};
        D1 = __builtin_amdgcn_mfma_f32_32x32x16_bf16(A1h.s, B1h.s, D1, 0, 0, 0);
        D1 = __builtin_amdgcn_mfma_f32_32x32x16_bf16(A1h.s, B1l.s, D1, 0, 0, 0);
        D1 = __builtin_amdgcn_mfma_f32_32x32x16_bf16(A1l.s, B1h.s, D1, 0, 0, 0);
        D1 = __builtin_amdgcn_mfma_f32_32x32x16_bf16(A1l.s, B1l.s, D1, 0, 0, 0);

        // ---- elementwise: r2' = D1 + zz/mu^2 (fp32!) ; w = rsq(r2') = mu/r ----
        float wv[16];
        #pragma unroll
        for (int r = 0; r < 16; ++r) {
            float r2 = fmaf(zz, imv[r], D1[r]);
            wv[r] = __builtin_amdgcn_rsqf(r2);
        }
        float t0 = wv[0] + wv[1],   t1 = wv[2] + wv[3],   t2 = wv[4] + wv[5],   t3 = wv[6] + wv[7];
        float t4 = wv[8] + wv[9],   t5 = wv[10] + wv[11], t6 = wv[12] + wv[13], t7 = wv[14] + wv[15];
        float n_half = ((t0 + t1) + (t2 + t3)) + ((t4 + t5) + (t6 + t7));
        float w3v[16];
        #pragma unroll
        for (int r = 0; r < 16; ++r) w3v[r] = (wv[r] * wv[r]) * wv[r];

        // ---- pack w^3 (hi AND lo split) into B2 fragments via shfl half-exchange ----
        uint32_t Ph[8], Pl[8];
        #pragma unroll
        for (int j = 0; j < 8; ++j) {
            float a = w3v[2 * j], b = w3v[2 * j + 1];
            Ph[j] = pkbf16(a, b);
            Pl[j] = pkbf16(a - lo16f(Ph[j]), b - hi16f(Ph[j]));
        }
        uint32_t Php[8], Plp[8];
        #pragma unroll
        for (int j = 0; j < 8; ++j) { Php[j] = sx32u(Ph[j]); Plp[j] = sx32u(Pl[j]); }

        FragU B2c0h, B2c1h, B2c0l, B2c1l;
        B2c0h.u[0] = hi ? Php[2] : Ph[0];  B2c0h.u[1] = hi ? Php[3] : Ph[1];
        B2c0h.u[2] = hi ? Ph[2] : Php[0];  B2c0h.u[3] = hi ? Ph[3] : Php[1];
        B2c1h.u[0] = hi ? Php[6] : Ph[4];  B2c1h.u[1] = hi ? Php[7] : Ph[5];
        B2c1h.u[2] = hi ? Ph[6] : Php[4];  B2c1h.u[3] = hi ? Ph[7] : Php[5];
        B2c0l.u[0] = hi ? Plp[2] : Pl[0];  B2c0l.u[1] = hi ? Plp[3] : Pl[1];
        B2c0l.u[2] = hi ? Pl[2] : Plp[0];  B2c0l.u[3] = hi ? Pl[3] : Plp[1];
        B2c1l.u[0] = hi ? Plp[6] : Pl[4];  B2c1l.u[1] = hi ? Plp[7] : Pl[5];
        B2c1l.u[2] = hi ? Pl[6] : Plp[4];  B2c1l.u[3] = hi ? Pl[7] : Plp[5];

        // ---- GEMM2: D2[row][point]; rows 0..7 = gc dims, row 8 = sw; 8-term split ----
        f32x16 D2 = {};
        D2 = __builtin_amdgcn_mfma_f32_32x32x16_bf16(A2h0.s, B2c0h.s, D2, 0, 0, 0);
        D2 = __builtin_amdgcn_mfma_f32_32x32x16_bf16(A2h1.s, B2c1h.s, D2, 0, 0, 0);
        D2 = __builtin_amdgcn_mfma_f32_32x32x16_bf16(A2l0.s, B2c0h.s, D2, 0, 0, 0);
        D2 = __builtin_amdgcn_mfma_f32_32x32x16_bf16(A2l1.s, B2c1h.s, D2, 0, 0, 0);
        D2 = __builtin_amdgcn_mfma_f32_32x32x16_bf16(A2h0.s, B2c0l.s, D2, 0, 0, 0);
        D2 = __builtin_amdgcn_mfma_f32_32x32x16_bf16(A2h1.s, B2c1l.s, D2, 0, 0, 0);
        D2 = __builtin_amdgcn_mfma_f32_32x32x16_bf16(A2l0.s, B2c0l.s, D2, 0, 0, 0);
        D2 = __builtin_amdgcn_mfma_f32_32x32x16_bf16(A2l1.s, B2c1l.s, D2, 0, 0, 0);

        // ---- epilogue ----
        float n  = 1.0f + n_half + sx32(n_half);
        float swp = D2[4];                    // hi0: row8 = sw ; hi1: row12 = 0
        float sw = swp + sx32(swp);
        float scale = DTB * __builtin_amdgcn_rcpf(n);

        float g0 = fmaf(-sw, za0, D2[0]);
        float g1 = fmaf(-sw, za1, D2[1]);
        float g2 = fmaf(-sw, za2, D2[2]);
        float g3 = fmaf(-sw, za3, D2[3]);
        za0 = fminf(fmaxf(fmaf(scale, g0, za0), -CLAMPV), CLAMPV);
        za1 = fminf(fmaxf(fmaf(scale, g1, za1), -CLAMPV), CLAMPV);
        za2 = fminf(fmaxf(fmaf(scale, g2, za2), -CLAMPV), CLAMPV);
        za3 = fminf(fmaxf(fmaf(scale, g3, za3), -CLAMPV), CLAMPV);
        zb0 = sx32(za0); zb1 = sx32(za1); zb2 = sx32(za2); zb3 = sx32(za3);
    }

    float4* op = (float4*)out;
    op[(size_t)point * 2 + hi] = make_float4(za0, za1, za2, za3);
}

extern "C" void kernel_launch(void* const* d_in, const int* in_sizes, int n_in,
                              void* d_out, int out_size, void* d_ws, size_t ws_size,
                              hipStream_t stream) {
    const float* z       = (const float*)d_in[0];
    const float* centers = (const float*)d_in[1];
    const float* mus     = (const float*)d_in[2];
    float* out           = (float*)d_out;
    uint4* wsu           = (uint4*)d_ws;

    prep_kernel<<<1, 64, 0, stream>>>(centers, mus, wsu);
    pm_kernel<<<NB / 128, 256, 0, stream>>>(z, wsu, out);   // 4096 blocks, 32 pts/wave
}

// Round 14
// 38.934 us; speedup vs baseline: 1.9793x; 1.0663x over previous
//
#include <hip/hip_runtime.h>
#include <stdint.h>

#define NB 524288
#define NC 32
#define EPSV 1e-4f
#define DTB 0.12f      // DT * BETA
#define CLAMPV 3.0f
#define NSTEPS 4

typedef float f32x16 __attribute__((ext_vector_type(16)));
typedef short short8 __attribute__((ext_vector_type(8)));

union FragU { uint32_t u[4]; short8 s; uint4 q; };

__device__ __forceinline__ uint32_t pkbf16(float a, float b) {
    uint32_t r;
    asm("v_cvt_pk_bf16_f32 %0, %1, %2" : "=v"(r) : "v"(a), "v"(b));
    return r;   // low16 = bf16(a), high16 = bf16(b)
}
__device__ __forceinline__ float lo16f(uint32_t w) { return __uint_as_float(w << 16); }
__device__ __forceinline__ float hi16f(uint32_t w) { return __uint_as_float(w & 0xffff0000u); }
__device__ __forceinline__ float sx32(float v) { return __shfl_xor(v, 32); }

// ws layout:
//  uint4 [0..63]    A1_hi : rows=centers, k<8: -2c/mu^2, k=8: (|c|^2+eps)/mu^2, k>=9: 0
//  uint4 [64..127]  A1_lo
//  uint4 [128..191] A2_hi chunk0 : rows 0..7 = c_d/mu^2, row 8 = 1/mu^2; k-axis PERMUTED:
//                   center(ch,k) = ch*16 + (k&3) + 8*((k>>2)&1) + 4*(k>>3)
//                   (each half-wave's B2 k-slots == its own D1-register centers -> no shfl)
//  uint4 [192..255] A2_hi chunk1
//  uint4 [256..319] A2_lo chunk0
//  uint4 [320..383] A2_lo chunk1
//  float [1536..1567] imtab: imtab[h*16+r] = 1/mu^2 of center crow(r,h)=(r&3)+8*(r>>2)+4*h
__global__ void prep_kernel(const float* __restrict__ centers,
                            const float* __restrict__ mus,
                            uint4* __restrict__ wsu) {
    int t = threadIdx.x;
    if (t >= 64) return;
    int row = t & 31, part = t >> 5;

    // ---- A1 (rows = centers) ----
    float mu = mus[row];
    float im2 = 1.0f / (mu * mu);
    float c[8];
    float bb = EPSV;
    #pragma unroll
    for (int d = 0; d < 8; ++d) { c[d] = centers[row * 8 + d]; bb = fmaf(c[d], c[d], bb); }
    float v[8];
    #pragma unroll
    for (int i = 0; i < 8; ++i) {
        int k = part * 8 + i;
        v[i] = (k < 8) ? (-2.0f * c[k] * im2) : (k == 8) ? (bb * im2) : 0.0f;
    }
    uint32_t h[4], l[4];
    #pragma unroll
    for (int j = 0; j < 4; ++j) {
        float a = v[2 * j], b = v[2 * j + 1];
        h[j] = pkbf16(a, b);
        l[j] = pkbf16(a - lo16f(h[j]), b - hi16f(h[j]));
    }
    wsu[t]      = make_uint4(h[0], h[1], h[2], h[3]);
    wsu[64 + t] = make_uint4(l[0], l[1], l[2], l[3]);

    // ---- A2 (rows 0..7 = c_d/mu^2, row 8 = 1/mu^2; k-axis permuted) ----
    #pragma unroll
    for (int ch = 0; ch < 2; ++ch) {
        float v2[8];
        #pragma unroll
        for (int i = 0; i < 8; ++i) {
            int k = part * 8 + i;
            int within = (k & 3) + 8 * ((k >> 2) & 1) + 4 * (k >> 3);
            int ci = ch * 16 + within;
            float muc = mus[ci];
            float im2c = 1.0f / (muc * muc);
            v2[i] = (row < 8) ? (centers[ci * 8 + row] * im2c) : (row == 8) ? im2c : 0.0f;
        }
        uint32_t h2[4], l2[4];
        #pragma unroll
        for (int j = 0; j < 4; ++j) {
            float a = v2[2 * j], b = v2[2 * j + 1];
            h2[j] = pkbf16(a, b);
            l2[j] = pkbf16(a - lo16f(h2[j]), b - hi16f(h2[j]));
        }
        wsu[128 + ch * 64 + t] = make_uint4(h2[0], h2[1], h2[2], h2[3]);
        wsu[256 + ch * 64 + t] = make_uint4(l2[0], l2[1], l2[2], l2[3]);
    }

    // ---- imtab ----
    if (t < 32) {
        int h2i = t >> 4, r = t & 15;
        int ci = (r & 3) + 8 * (r >> 2) + 4 * h2i;
        float muc = mus[ci];
        ((float*)wsu)[1536 + t] = 1.0f / (muc * muc);
    }
}

__global__ __launch_bounds__(256, 3) void pm_kernel(
    const float* __restrict__ z_in,
    const uint4* __restrict__ wsu,
    float* __restrict__ out)
{
    const int tid  = threadIdx.x;
    const int wid  = tid >> 6;
    const int lane = tid & 63;
    const int hi   = lane >> 5;          // half-wave id
    const int col  = lane & 31;          // point within tile
    const int point = blockIdx.x * 128 + wid * 32 + col;

    // constant fragments (L2-resident)
    FragU A1h, A1l, A2h0, A2h1, A2l0, A2l1;
    A1h.q  = wsu[lane];        A1l.q  = wsu[64 + lane];
    A2h0.q = wsu[128 + lane];  A2h1.q = wsu[192 + lane];
    A2l0.q = wsu[256 + lane];  A2l1.q = wsu[320 + lane];

    // per-lane fp32 constants: imv[r] = 1/mu^2 of center crow(r,hi)
    const float* imt = ((const float*)wsu) + 1536 + hi * 16;
    float imv[16];
    #pragma unroll
    for (int r = 0; r < 16; ++r) imv[r] = imt[r];

    // z: this lane owns dims [hi*4 .. hi*4+3] (za); partner half via shfl (zb)
    const float4* zp4 = (const float4*)z_in;
    float4 hvec = zp4[(size_t)point * 2 + hi];
    float za0 = hvec.x, za1 = hvec.y, za2 = hvec.z, za3 = hvec.w;
    float zb0 = sx32(za0), zb1 = sx32(za1), zb2 = sx32(za2), zb3 = sx32(za3);

    #pragma unroll 1
    for (int s = 0; s < NSTEPS; ++s) {
        // zz = |z|^2 (fp32, stays OUT of the bf16 GEMM)
        float zz = za0 * za0;
        zz = fmaf(za1, za1, zz); zz = fmaf(za2, za2, zz); zz = fmaf(za3, za3, zz);
        zz = fmaf(zb0, zb0, zz); zz = fmaf(zb1, zb1, zz);
        zz = fmaf(zb2, zb2, zz); zz = fmaf(zb3, zb3, zz);

        // ---- B1 (z_ext, col = point): hi0 lanes carry z dims 0..7; hi1 carry [1,0,...] ----
        uint32_t w0 = pkbf16(za0, za1), w1 = pkbf16(za2, za3);
        uint32_t w2 = pkbf16(zb0, zb1), w3w = pkbf16(zb2, zb3);
        uint32_t q0 = pkbf16(1.0f, 0.0f);   // k=8: exact 1; k=9: 0
        uint32_t w0l = pkbf16(za0 - lo16f(w0), za1 - hi16f(w0));
        uint32_t w1l = pkbf16(za2 - lo16f(w1), za3 - hi16f(w1));
        uint32_t w2l = pkbf16(zb0 - lo16f(w2), zb1 - hi16f(w2));
        uint32_t w3l = pkbf16(zb2 - lo16f(w3w), zb3 - hi16f(w3w));

        FragU B1h, B1l;
        B1h.u[0] = hi ? q0 : w0;   B1h.u[1] = hi ? 0u : w1;
        B1h.u[2] = hi ? 0u : w2;   B1h.u[3] = hi ? 0u : w3w;
        B1l.u[0] = hi ? 0u : w0l;  B1l.u[1] = hi ? 0u : w1l;
        B1l.u[2] = hi ? 0u : w2l;  B1l.u[3] = hi ? 0u : w3l;

        // ---- GEMM1: D1[center][point] = (bb - 2 z.c)/mu^2, full 4-term split ----
        f32x16 D1 = {};
        D1 = __builtin_amdgcn_mfma_f32_32x32x16_bf16(A1h.s, B1h.s, D1, 0, 0, 0);
        D1 = __builtin_amdgcn_mfma_f32_32x32x16_bf16(A1h.s, B1l.s, D1, 0, 0, 0);
        D1 = __builtin_amdgcn_mfma_f32_32x32x16_bf16(A1l.s, B1h.s, D1, 0, 0, 0);
        D1 = __builtin_amdgcn_mfma_f32_32x32x16_bf16(A1l.s, B1l.s, D1, 0, 0, 0);

        // ---- elementwise: r2' = D1 + zz/mu^2 (fp32) ; w = rsq(r2') = mu/r ----
        float wv[16];
        #pragma unroll
        for (int r = 0; r < 16; ++r) {
            float r2 = fmaf(zz, imv[r], D1[r]);
            wv[r] = __builtin_amdgcn_rsqf(r2);
        }
        float t0 = wv[0] + wv[1],   t1 = wv[2] + wv[3],   t2 = wv[4] + wv[5],   t3 = wv[6] + wv[7];
        float t4 = wv[8] + wv[9],   t5 = wv[10] + wv[11], t6 = wv[12] + wv[13], t7 = wv[14] + wv[15];
        float n_half = ((t0 + t1) + (t2 + t3)) + ((t4 + t5) + (t6 + t7));
        float w3v[16];
        #pragma unroll
        for (int r = 0; r < 16; ++r) w3v[r] = (wv[r] * wv[r]) * wv[r];

        // ---- B2 pack: PURE LOCAL (A2 k-axis permuted to match register ownership) ----
        FragU B2c0h, B2c1h, B2c0l, B2c1l;
        #pragma unroll
        for (int j = 0; j < 4; ++j) {
            float a = w3v[2 * j], b = w3v[2 * j + 1];
            uint32_t ph = pkbf16(a, b);
            B2c0h.u[j] = ph;
            B2c0l.u[j] = pkbf16(a - lo16f(ph), b - hi16f(ph));
        }
        #pragma unroll
        for (int j = 0; j < 4; ++j) {
            float a = w3v[8 + 2 * j], b = w3v[8 + 2 * j + 1];
            uint32_t ph = pkbf16(a, b);
            B2c1h.u[j] = ph;
            B2c1l.u[j] = pkbf16(a - lo16f(ph), b - hi16f(ph));
        }

        // ---- GEMM2: D2[row][point]; rows 0..7 = gc dims, row 8 = sw; 8-term split ----
        f32x16 D2 = {};
        D2 = __builtin_amdgcn_mfma_f32_32x32x16_bf16(A2h0.s, B2c0h.s, D2, 0, 0, 0);
        D2 = __builtin_amdgcn_mfma_f32_32x32x16_bf16(A2h1.s, B2c1h.s, D2, 0, 0, 0);
        D2 = __builtin_amdgcn_mfma_f32_32x32x16_bf16(A2l0.s, B2c0h.s, D2, 0, 0, 0);
        D2 = __builtin_amdgcn_mfma_f32_32x32x16_bf16(A2l1.s, B2c1h.s, D2, 0, 0, 0);
        D2 = __builtin_amdgcn_mfma_f32_32x32x16_bf16(A2h0.s, B2c0l.s, D2, 0, 0, 0);
        D2 = __builtin_amdgcn_mfma_f32_32x32x16_bf16(A2h1.s, B2c1l.s, D2, 0, 0, 0);
        D2 = __builtin_amdgcn_mfma_f32_32x32x16_bf16(A2l0.s, B2c0l.s, D2, 0, 0, 0);
        D2 = __builtin_amdgcn_mfma_f32_32x32x16_bf16(A2l1.s, B2c1l.s, D2, 0, 0, 0);

        // ---- epilogue ----
        float n  = 1.0f + n_half + sx32(n_half);
        float swp = D2[4];                    // hi0: row8 = sw ; hi1: row12 = 0
        float sw = swp + sx32(swp);
        float scale = DTB * __builtin_amdgcn_rcpf(n);

        float g0 = fmaf(-sw, za0, D2[0]);
        float g1 = fmaf(-sw, za1, D2[1]);
        float g2 = fmaf(-sw, za2, D2[2]);
        float g3 = fmaf(-sw, za3, D2[3]);
        za0 = fminf(fmaxf(fmaf(scale, g0, za0), -CLAMPV), CLAMPV);
        za1 = fminf(fmaxf(fmaf(scale, g1, za1), -CLAMPV), CLAMPV);
        za2 = fminf(fmaxf(fmaf(scale, g2, za2), -CLAMPV), CLAMPV);
        za3 = fminf(fmaxf(fmaf(scale, g3, za3), -CLAMPV), CLAMPV);
        zb0 = sx32(za0); zb1 = sx32(za1); zb2 = sx32(za2); zb3 = sx32(za3);
    }

    float4* op = (float4*)out;
    op[(size_t)point * 2 + hi] = make_float4(za0, za1, za2, za3);
}

extern "C" void kernel_launch(void* const* d_in, const int* in_sizes, int n_in,
                              void* d_out, int out_size, void* d_ws, size_t ws_size,
                              hipStream_t stream) {
    const float* z       = (const float*)d_in[0];
    const float* centers = (const float*)d_in[1];
    const float* mus     = (const float*)d_in[2];
    float* out           = (float*)d_out;
    uint4* wsu           = (uint4*)d_ws;

    prep_kernel<<<1, 64, 0, stream>>>(centers, mus, wsu);
    pm_kernel<<<NB / 128, 256, 0, stream>>>(z, wsu, out);   // 4096 blocks, 32 pts/wave
}

// Round 18
// 38.679 us; speedup vs baseline: 1.9923x; 1.0066x over previous
//
#include <hip/hip_runtime.h>
#include <stdint.h>

#define NB 524288
#define NC 32
#define EPSV 1e-4f
#define DTB 0.12f      // DT * BETA
#define CLAMPV 3.0f
#define NSTEPS 4

typedef float f32x16 __attribute__((ext_vector_type(16)));
typedef short short8 __attribute__((ext_vector_type(8)));

union FragU { uint32_t u[4]; short8 s; uint4 q; };

__device__ __forceinline__ uint32_t pkbf16(float a, float b) {
    uint32_t r;
    asm("v_cvt_pk_bf16_f32 %0, %1, %2" : "=v"(r) : "v"(a), "v"(b));
    return r;   // low16 = bf16(a), high16 = bf16(b)
}
__device__ __forceinline__ float lo16f(uint32_t w) { return __uint_as_float(w << 16); }
__device__ __forceinline__ float hi16f(uint32_t w) { return __uint_as_float(w & 0xffff0000u); }
__device__ __forceinline__ float sx32(float v) { return __shfl_xor(v, 32); }

// ws layout:
//  uint4 [0..63]    A1_hi : rows=centers, k<8: -2c/mu^2, k=8: (|c|^2+eps)/mu^2, k>=9: 0
//  uint4 [64..127]  A1_lo
//  uint4 [128..191] A2_hi chunk0 : rows 0..7 = c_d/mu^2, row 8 = 1/mu^2; k-axis PERMUTED:
//                   center(ch,k) = ch*16 + (k&3) + 8*((k>>2)&1) + 4*(k>>3)
//  uint4 [192..255] A2_hi chunk1
//  uint4 [256..319] A2_lo chunk0
//  uint4 [320..383] A2_lo chunk1
//  float [1536..1567] imtab: imtab[h*16+r] = 1/mu^2 of center crow(r,h)=(r&3)+8*(r>>2)+4*h
__global__ void prep_kernel(const float* __restrict__ centers,
                            const float* __restrict__ mus,
                            uint4* __restrict__ wsu) {
    int t = threadIdx.x;
    if (t >= 64) return;
    int row = t & 31, part = t >> 5;

    float mu = mus[row];
    float im2 = 1.0f / (mu * mu);
    float c[8];
    float bb = EPSV;
    #pragma unroll
    for (int d = 0; d < 8; ++d) { c[d] = centers[row * 8 + d]; bb = fmaf(c[d], c[d], bb); }
    float v[8];
    #pragma unroll
    for (int i = 0; i < 8; ++i) {
        int k = part * 8 + i;
        v[i] = (k < 8) ? (-2.0f * c[k] * im2) : (k == 8) ? (bb * im2) : 0.0f;
    }
    uint32_t h[4], l[4];
    #pragma unroll
    for (int j = 0; j < 4; ++j) {
        float a = v[2 * j], b = v[2 * j + 1];
        h[j] = pkbf16(a, b);
        l[j] = pkbf16(a - lo16f(h[j]), b - hi16f(h[j]));
    }
    wsu[t]      = make_uint4(h[0], h[1], h[2], h[3]);
    wsu[64 + t] = make_uint4(l[0], l[1], l[2], l[3]);

    #pragma unroll
    for (int ch = 0; ch < 2; ++ch) {
        float v2[8];
        #pragma unroll
        for (int i = 0; i < 8; ++i) {
            int k = part * 8 + i;
            int within = (k & 3) + 8 * ((k >> 2) & 1) + 4 * (k >> 3);
            int ci = ch * 16 + within;
            float muc = mus[ci];
            float im2c = 1.0f / (muc * muc);
            v2[i] = (row < 8) ? (centers[ci * 8 + row] * im2c) : (row == 8) ? im2c : 0.0f;
        }
        uint32_t h2[4], l2[4];
        #pragma unroll
        for (int j = 0; j < 4; ++j) {
            float a = v2[2 * j], b = v2[2 * j + 1];
            h2[j] = pkbf16(a, b);
            l2[j] = pkbf16(a - lo16f(h2[j]), b - hi16f(h2[j]));
        }
        wsu[128 + ch * 64 + t] = make_uint4(h2[0], h2[1], h2[2], h2[3]);
        wsu[256 + ch * 64 + t] = make_uint4(l2[0], l2[1], l2[2], l2[3]);
    }

    if (t < 32) {
        int h2i = t >> 4, r = t & 15;
        int ci = (r & 3) + 8 * (r >> 2) + 4 * h2i;
        float muc = mus[ci];
        ((float*)wsu)[1536 + t] = 1.0f / (muc * muc);
    }
}

__global__ __launch_bounds__(256, 4) void pm_kernel(
    const float* __restrict__ z_in,
    const uint4* __restrict__ wsu,
    float* __restrict__ out)
{
    const int tid  = threadIdx.x;
    const int wid  = tid >> 6;
    const int lane = tid & 63;
    const int hi   = lane >> 5;          // half-wave id
    const int col  = lane & 31;          // point within tile
    const int point = blockIdx.x * 128 + wid * 32 + col;

    // constant fragments (L2-resident)
    FragU A1h, A1l, A2h0, A2h1, A2l0, A2l1;
    A1h.q  = wsu[lane];        A1l.q  = wsu[64 + lane];
    A2h0.q = wsu[128 + lane];  A2h1.q = wsu[192 + lane];
    A2l0.q = wsu[256 + lane];  A2l1.q = wsu[320 + lane];

    // per-lane fp32 constants: imv[r] = 1/mu^2 of center crow(r,hi)
    const float* imt = ((const float*)wsu) + 1536 + hi * 16;
    float imv[16];
    #pragma unroll
    for (int r = 0; r < 16; ++r) imv[r] = imt[r];

    // z: this lane owns dims [hi*4 .. hi*4+3] (za); partner half via shfl (zb)
    const float4* zp4 = (const float4*)z_in;
    float4 hvec = zp4[(size_t)point * 2 + hi];
    float za0 = hvec.x, za1 = hvec.y, za2 = hvec.z, za3 = hvec.w;
    float zb0 = sx32(za0), zb1 = sx32(za1), zb2 = sx32(za2), zb3 = sx32(za3);

    #pragma unroll 1
    for (int s = 0; s < NSTEPS; ++s) {
        // zz = |z|^2 (fp32, stays OUT of the bf16 GEMM)
        float zz = za0 * za0;
        zz = fmaf(za1, za1, zz); zz = fmaf(za2, za2, zz); zz = fmaf(za3, za3, zz);
        zz = fmaf(zb0, zb0, zz); zz = fmaf(zb1, zb1, zz);
        zz = fmaf(zb2, zb2, zz); zz = fmaf(zb3, zb3, zz);

        // ---- B1 (z_ext, col = point): hi0 lanes carry z dims 0..7; hi1 carry [1,0,...] ----
        uint32_t w0 = pkbf16(za0, za1), w1 = pkbf16(za2, za3);
        uint32_t w2 = pkbf16(zb0, zb1), w3w = pkbf16(zb2, zb3);
        uint32_t q0 = pkbf16(1.0f, 0.0f);   // k=8: exact 1; k=9: 0
        uint32_t w0l = pkbf16(za0 - lo16f(w0), za1 - hi16f(w0));
        uint32_t w1l = pkbf16(za2 - lo16f(w1), za3 - hi16f(w1));
        uint32_t w2l = pkbf16(zb0 - lo16f(w2), zb1 - hi16f(w2));
        uint32_t w3l = pkbf16(zb2 - lo16f(w3w), zb3 - hi16f(w3w));

        FragU B1h, B1l;
        B1h.u[0] = hi ? q0 : w0;   B1h.u[1] = hi ? 0u : w1;
        B1h.u[2] = hi ? 0u : w2;   B1h.u[3] = hi ? 0u : w3w;
        B1l.u[0] = hi ? 0u : w0l;  B1l.u[1] = hi ? 0u : w1l;
        B1l.u[2] = hi ? 0u : w2l;  B1l.u[3] = hi ? 0u : w3l;

        // ---- GEMM1: D1[center][point] = (bb - 2 z.c)/mu^2, full 4-term split (r14-exact) ----
        f32x16 D1 = {};
        D1 = __builtin_amdgcn_mfma_f32_32x32x16_bf16(A1h.s, B1h.s, D1, 0, 0, 0);
        D1 = __builtin_amdgcn_mfma_f32_32x32x16_bf16(A1h.s, B1l.s, D1, 0, 0, 0);
        D1 = __builtin_amdgcn_mfma_f32_32x32x16_bf16(A1l.s, B1h.s, D1, 0, 0, 0);
        D1 = __builtin_amdgcn_mfma_f32_32x32x16_bf16(A1l.s, B1l.s, D1, 0, 0, 0);

        // ---- elementwise: r2' = D1 + zz/mu^2 (fp32) ; w = rsq(r2') = mu/r ----
        float wv[16];
        #pragma unroll
        for (int r = 0; r < 16; ++r) {
            float r2 = fmaf(zz, imv[r], D1[r]);
            wv[r] = __builtin_amdgcn_rsqf(r2);
        }
        float t0 = wv[0] + wv[1],   t1 = wv[2] + wv[3],   t2 = wv[4] + wv[5],   t3 = wv[6] + wv[7];
        float t4 = wv[8] + wv[9],   t5 = wv[10] + wv[11], t6 = wv[12] + wv[13], t7 = wv[14] + wv[15];
        float n_half = ((t0 + t1) + (t2 + t3)) + ((t4 + t5) + (t6 + t7));
        float w3v[16];
        #pragma unroll
        for (int r = 0; r < 16; ++r) w3v[r] = (wv[r] * wv[r]) * wv[r];

        // ---- B2 pack: pure local, WITH lo-residual (r14-exact) ----
        FragU B2c0h, B2c1h, B2c0l, B2c1l;
        #pragma unroll
        for (int j = 0; j < 4; ++j) {
            float a = w3v[2 * j], b = w3v[2 * j + 1];
            uint32_t ph = pkbf16(a, b);
            B2c0h.u[j] = ph;
            B2c0l.u[j] = pkbf16(a - lo16f(ph), b - hi16f(ph));
        }
        #pragma unroll
        for (int j = 0; j < 4; ++j) {
            float a = w3v[8 + 2 * j], b = w3v[8 + 2 * j + 1];
            uint32_t ph = pkbf16(a, b);
            B2c1h.u[j] = ph;
            B2c1l.u[j] = pkbf16(a - lo16f(ph), b - hi16f(ph));
        }

        // ---- GEMM2: 8-term split (r14-exact) ----
        f32x16 D2 = {};
        D2 = __builtin_amdgcn_mfma_f32_32x32x16_bf16(A2h0.s, B2c0h.s, D2, 0, 0, 0);
        D2 = __builtin_amdgcn_mfma_f32_32x32x16_bf16(A2h1.s, B2c1h.s, D2, 0, 0, 0);
        D2 = __builtin_amdgcn_mfma_f32_32x32x16_bf16(A2l0.s, B2c0h.s, D2, 0, 0, 0);
        D2 = __builtin_amdgcn_mfma_f32_32x32x16_bf16(A2l1.s, B2c1h.s, D2, 0, 0, 0);
        D2 = __builtin_amdgcn_mfma_f32_32x32x16_bf16(A2h0.s, B2c0l.s, D2, 0, 0, 0);
        D2 = __builtin_amdgcn_mfma_f32_32x32x16_bf16(A2h1.s, B2c1l.s, D2, 0, 0, 0);
        D2 = __builtin_amdgcn_mfma_f32_32x32x16_bf16(A2l0.s, B2c0l.s, D2, 0, 0, 0);
        D2 = __builtin_amdgcn_mfma_f32_32x32x16_bf16(A2l1.s, B2c1l.s, D2, 0, 0, 0);

        // ---- epilogue ----
        float n  = 1.0f + n_half + sx32(n_half);
        float swp = D2[4];                    // hi0: row8 = sw ; hi1: row12 = 0
        float sw = swp + sx32(swp);
        float scale = DTB * __builtin_amdgcn_rcpf(n);

        float g0 = fmaf(-sw, za0, D2[0]);
        float g1 = fmaf(-sw, za1, D2[1]);
        float g2 = fmaf(-sw, za2, D2[2]);
        float g3 = fmaf(-sw, za3, D2[3]);
        za0 = fminf(fmaxf(fmaf(scale, g0, za0), -CLAMPV), CLAMPV);
        za1 = fminf(fmaxf(fmaf(scale, g1, za1), -CLAMPV), CLAMPV);
        za2 = fminf(fmaxf(fmaf(scale, g2, za2), -CLAMPV), CLAMPV);
        za3 = fminf(fmaxf(fmaf(scale, g3, za3), -CLAMPV), CLAMPV);
        zb0 = sx32(za0); zb1 = sx32(za1); zb2 = sx32(za2); zb3 = sx32(za3);
    }

    float4* op = (float4*)out;
    op[(size_t)point * 2 + hi] = make_float4(za0, za1, za2, za3);
}

extern "C" void kernel_launch(void* const* d_in, const int* in_sizes, int n_in,
                              void* d_out, int out_size, void* d_ws, size_t ws_size,
                              hipStream_t stream) {
    const float* z       = (const float*)d_in[0];
    const float* centers = (const float*)d_in[1];
    const float* mus     = (const float*)d_in[2];
    float* out           = (float*)d_out;
    uint4* wsu           = (uint4*)d_ws;

    prep_kernel<<<1, 64, 0, stream>>>(centers, mus, wsu);
    pm_kernel<<<NB / 128, 256, 0, stream>>>(z, wsu, out);   // 4096 blocks, 32 pts/wave
}